// Round 8
// baseline (77.434 us; speedup 1.0000x reference)
//
#include <hip/hip_runtime.h>
#include <math.h>

#define N_POINTS 8192
#define N_PAIRS  262144

constexpr int BLOCKS  = 512;
constexpr int THREADS = 256;
constexpr int TILE    = 8;                    // rows per virtual tile
constexpr int NTILES  = N_POINTS / TILE;      // 1024 tiles; block b does {b, 1023-b}
constexpr int EPB     = N_PAIRS / BLOCKS;     // 512 edges per block

typedef float f32x2 __attribute__((ext_vector_type(2)));

// ---------------- Single fused kernel (R7 body + fence-free ticket tail) ----
// Phase 1: tile v = rows [8v,8v+8) sweeps columns k in [8v, N), two columns
// per iteration (packed fp32). S_all = 2*T - sum_v D_v. Block b handles tiles
// b and 1023-b -> exactly 8200 swept columns per block.
// Phase 2: block's 512-edge slice; edge/pij prefetched before phase 1.
// Tail: partials are published with AGENT-scope relaxed atomic stores
// (write-through to the coherence point -> no buffer_wbl2 L2 flush, which is
// what made R6's __threadfence() version regress by ~5us right after the
// harness's 268MB poison dirtied L2). Ordering store->ticket via
// s_waitcnt vmcnt(0); ticket RMWs are totally ordered, so the last arriver
// observes all published partials. Ticket zeroed by a 4B hipMemsetAsync.
__global__ __launch_bounds__(THREADS)
void fused_kernel(const float* __restrict__ logits,
                  const float* __restrict__ pij,
                  const int* __restrict__ ei,
                  const int* __restrict__ ej,
                  unsigned int* __restrict__ ticket,
                  float* __restrict__ partials,
                  float* __restrict__ out) {
    __shared__ float2 pts[N_POINTS];             // 64 KiB -> 2 blocks/CU
    __shared__ float wred[3][THREADS / 64];
    __shared__ double dred[3][4];
    __shared__ int is_last;

    const int t = threadIdx.x;
    const int b = blockIdx.x;

    // cooperative stage: 4096 float4, coalesced; src is 64 KB -> L2/L3 hot
    {
        const float4* src = (const float4*)logits;
        float4* dst = (float4*)pts;
        #pragma unroll
        for (int k = t; k < N_POINTS / 2; k += THREADS) dst[k] = src[k];
    }

    // edge prefetch: independent of LDS, issues under the staging loads
    const int2   ea = ((const int2*)(ei + b * EPB))[t];
    const int2   eb = ((const int2*)(ej + b * EPB))[t];
    const float2 pp = ((const float2*)(pij + b * EPB))[t];

    __syncthreads();

    const int v1 = b;
    const int v2 = NTILES - 1 - b;

    // ---- phase 1: packed wedge sweep (8 rows x 2 columns per iteration) ----
    auto sweep = [&](int v) -> float {
        const int r0 = v * TILE;
        f32x2 rxv[TILE], ryv[TILE], acc[TILE];
        #pragma unroll
        for (int r = 0; r < TILE; ++r) {
            const float2 pr = pts[r0 + r];
            rxv[r] = (f32x2){pr.x, pr.x};
            ryv[r] = (f32x2){pr.y, pr.y};
            acc[r] = (f32x2){0.0f, 0.0f};
        }
        // columns r0..N-1: count is a multiple of 8, so pairs never split
        #pragma unroll 2
        for (int k = r0 + 2 * t; k < N_POINTS; k += 2 * THREADS) {
            const float4 qq = *(const float4*)&pts[k];   // points k, k+1 (b128)
            const f32x2 qx = (f32x2){qq.x, qq.z};
            const f32x2 qy = (f32x2){qq.y, qq.w};
            #pragma unroll
            for (int r = 0; r < TILE; ++r) {
                const f32x2 dx = rxv[r] - qx;
                const f32x2 dy = ryv[r] - qy;
                const f32x2 d2 = dx * dx + dy * dy + 1.0f;
                acc[r] += (f32x2){__builtin_amdgcn_rcpf(d2.x),
                                  __builtin_amdgcn_rcpf(d2.y)};
            }
        }
        float s = 0.0f;
        #pragma unroll
        for (int r = 0; r < TILE; ++r) s += acc[r].x + acc[r].y;
        return s;
    };

    float T = sweep(v1) + sweep(v2);

    // diagonal 8x8 squares: 64 pairs per tile, one per lane (waves 0 and 1)
    float Dc = 0.0f;
    if (t < 128) {
        const int v = (t < 64) ? v1 : v2;
        const int l = t & 63;
        const int i = v * TILE + (l >> 3);
        const int k = v * TILE + (l & 7);
        const float dx = pts[i].x - pts[k].x;
        const float dy = pts[i].y - pts[k].y;
        const float d2 = __builtin_fmaf(dx, dx, __builtin_fmaf(dy, dy, 1.0f));
        Dc = __builtin_amdgcn_rcpf(d2);
    }
    float part = __builtin_fmaf(2.0f, T, -Dc);   // block share of S_all

    // ---- phase 2: edge math on prefetched registers; points from LDS ----
    float s1 = 0.0f, sp = 0.0f;
    {
        float2 pa = pts[ea.x], pb = pts[eb.x];
        float dx = pa.x - pb.x, dy = pa.y - pb.y;
        float d2 = __builtin_fmaf(dx, dx, __builtin_fmaf(dy, dy, 2.0f));
        s1 += pp.x * (__logf(pp.x) + __logf(d2));
        sp += pp.x;

        pa = pts[ea.y]; pb = pts[eb.y];
        dx = pa.x - pb.x; dy = pa.y - pb.y;
        d2 = __builtin_fmaf(dx, dx, __builtin_fmaf(dy, dy, 2.0f));
        s1 += pp.y * (__logf(pp.y) + __logf(d2));
        sp += pp.y;
    }

    // ---- block reduction ----
    #pragma unroll
    for (int off = 32; off > 0; off >>= 1) {
        part += __shfl_down(part, off, 64);
        s1   += __shfl_down(s1,   off, 64);
        sp   += __shfl_down(sp,   off, 64);
    }
    const int w = t >> 6, l = t & 63;
    if (l == 0) { wred[0][w] = part; wred[1][w] = s1; wred[2][w] = sp; }
    __syncthreads();
    if (t == 0) {
        float r0s = 0.f, r1s = 0.f, r2s = 0.f;
        #pragma unroll
        for (int i = 0; i < THREADS / 64; ++i) {
            r0s += wred[0][i]; r1s += wred[1][i]; r2s += wred[2][i];
        }
        // publish via agent-scope atomic stores (coherent, no L2 flush)
        __hip_atomic_store(&partials[0 * BLOCKS + b], r0s,
                           __ATOMIC_RELAXED, __HIP_MEMORY_SCOPE_AGENT);
        __hip_atomic_store(&partials[1 * BLOCKS + b], r1s,
                           __ATOMIC_RELAXED, __HIP_MEMORY_SCOPE_AGENT);
        __hip_atomic_store(&partials[2 * BLOCKS + b], r2s,
                           __ATOMIC_RELAXED, __HIP_MEMORY_SCOPE_AGENT);
        __builtin_amdgcn_s_waitcnt(0);           // drain the stores (vmcnt)
        const unsigned int old = __hip_atomic_fetch_add(
            ticket, 1u, __ATOMIC_RELAXED, __HIP_MEMORY_SCOPE_AGENT);
        is_last = (old == (unsigned int)(BLOCKS - 1));
    }
    __syncthreads();

    // ---- tail: last-arriving block reduces all partials (double) ----
    if (is_last) {
        double a = 0.0, s = 0.0, p = 0.0;
        {
            const int u0 = t, u1 = t + THREADS;   // covers 512 entries
            a = (double)__hip_atomic_load(&partials[0 * BLOCKS + u0],
                    __ATOMIC_RELAXED, __HIP_MEMORY_SCOPE_AGENT)
              + (double)__hip_atomic_load(&partials[0 * BLOCKS + u1],
                    __ATOMIC_RELAXED, __HIP_MEMORY_SCOPE_AGENT);
            s = (double)__hip_atomic_load(&partials[1 * BLOCKS + u0],
                    __ATOMIC_RELAXED, __HIP_MEMORY_SCOPE_AGENT)
              + (double)__hip_atomic_load(&partials[1 * BLOCKS + u1],
                    __ATOMIC_RELAXED, __HIP_MEMORY_SCOPE_AGENT);
            p = (double)__hip_atomic_load(&partials[2 * BLOCKS + u0],
                    __ATOMIC_RELAXED, __HIP_MEMORY_SCOPE_AGENT)
              + (double)__hip_atomic_load(&partials[2 * BLOCKS + u1],
                    __ATOMIC_RELAXED, __HIP_MEMORY_SCOPE_AGENT);
        }
        #pragma unroll
        for (int off = 32; off > 0; off >>= 1) {
            a += __shfl_down(a, off, 64);
            s += __shfl_down(s, off, 64);
            p += __shfl_down(p, off, 64);
        }
        if (l == 0) { dred[0][w] = a; dred[1][w] = s; dred[2][w] = p; }
        __syncthreads();
        if (t == 0) {
            double A = 0.0, S = 0.0, P = 0.0;
            #pragma unroll
            for (int i = 0; i < THREADS / 64; ++i) {
                A += dred[0][i]; S += dred[1][i]; P += dred[2][i];
            }
            A -= (double)N_POINTS;               // remove diagonal (each term == 1)
            out[0] = (float)(S + log(A) * P);
        }
    }
}

extern "C" void kernel_launch(void* const* d_in, const int* in_sizes, int n_in,
                              void* d_out, int out_size, void* d_ws, size_t ws_size,
                              hipStream_t stream) {
    const float* pij    = (const float*)d_in[0];
    const int*   ei     = (const int*)d_in[1];
    const int*   ej     = (const int*)d_in[2];
    const float* logits = (const float*)d_in[3];
    float* out = (float*)d_out;

    unsigned int* ticket = (unsigned int*)d_ws;          // 4 B, zeroed below
    float* partials = (float*)((char*)d_ws + 64);        // 3 * BLOCKS floats

    hipMemsetAsync(ticket, 0, sizeof(unsigned int), stream);
    fused_kernel<<<BLOCKS, THREADS, 0, stream>>>(logits, pij, ei, ej,
                                                 ticket, partials, out);
}

// Round 9
// 72.513 us; speedup vs baseline: 1.0679x; 1.0679x over previous
//
#include <hip/hip_runtime.h>
#include <math.h>

#define N_POINTS 8192
#define N_PAIRS  262144

constexpr int BLOCKS  = 512;
constexpr int THREADS = 256;
constexpr int TILE    = 8;                    // rows per virtual tile
constexpr int NTILES  = N_POINTS / TILE;      // 1024 tiles; block b does {b, 1023-b}
constexpr int EPB     = N_PAIRS / BLOCKS;     // 512 edges per block

typedef float f32x2 __attribute__((ext_vector_type(2)));

// ---------------- Fused kernel (R7 structure — measured best, 72.77us) ------
// Phase 1: tile v = rows [8v,8v+8) sweeps columns k in [8v, N), two columns per
// iteration as a float2 vector (packed fp32), one ds_read_b128 feeds 16
// pair-evals. S_all = 2*T - sum_v D_v. Block b handles tiles b and 1023-b ->
// exactly 8200 swept columns per block (uniform work).
// Phase 2: block's 512-edge slice; edge/pij prefetched into registers BEFORE
// phase 1 so global latency hides under the sweep.
// NOTE (R6/R8 evidence): do NOT fuse the final reduction into this kernel via
// a last-arriving-block ticket — both the fenced (+7.5us) and fence-free
// (+4.6us) variants regressed vs the separate 1-block final_kernel.
__global__ __launch_bounds__(THREADS)
void fused_kernel(const float* __restrict__ logits,
                  const float* __restrict__ pij,
                  const int* __restrict__ ei,
                  const int* __restrict__ ej,
                  float* __restrict__ partials) {
    __shared__ float2 pts[N_POINTS];             // 64 KiB -> 2 blocks/CU
    __shared__ float wred[3][THREADS / 64];

    const int t = threadIdx.x;
    const int b = blockIdx.x;

    // cooperative stage: 4096 float4, coalesced; src is 64 KB -> L2/L3 hot
    {
        const float4* src = (const float4*)logits;
        float4* dst = (float4*)pts;
        #pragma unroll
        for (int k = t; k < N_POINTS / 2; k += THREADS) dst[k] = src[k];
    }

    // edge prefetch: independent of LDS, issues under the staging loads
    const int2   ea = ((const int2*)(ei + b * EPB))[t];
    const int2   eb = ((const int2*)(ej + b * EPB))[t];
    const float2 pp = ((const float2*)(pij + b * EPB))[t];

    __syncthreads();

    const int v1 = b;
    const int v2 = NTILES - 1 - b;

    // ---- phase 1: packed wedge sweep (8 rows x 2 columns per iteration) ----
    auto sweep = [&](int v) -> float {
        const int r0 = v * TILE;
        f32x2 rxv[TILE], ryv[TILE], acc[TILE];
        #pragma unroll
        for (int r = 0; r < TILE; ++r) {
            const float2 pr = pts[r0 + r];
            rxv[r] = (f32x2){pr.x, pr.x};
            ryv[r] = (f32x2){pr.y, pr.y};
            acc[r] = (f32x2){0.0f, 0.0f};
        }
        // columns r0..N-1: count is a multiple of 8, so pairs never split
        #pragma unroll 2
        for (int k = r0 + 2 * t; k < N_POINTS; k += 2 * THREADS) {
            const float4 qq = *(const float4*)&pts[k];   // points k, k+1 (b128)
            const f32x2 qx = (f32x2){qq.x, qq.z};
            const f32x2 qy = (f32x2){qq.y, qq.w};
            #pragma unroll
            for (int r = 0; r < TILE; ++r) {
                const f32x2 dx = rxv[r] - qx;
                const f32x2 dy = ryv[r] - qy;
                const f32x2 d2 = dx * dx + dy * dy + 1.0f;
                acc[r] += (f32x2){__builtin_amdgcn_rcpf(d2.x),
                                  __builtin_amdgcn_rcpf(d2.y)};
            }
        }
        float s = 0.0f;
        #pragma unroll
        for (int r = 0; r < TILE; ++r) s += acc[r].x + acc[r].y;
        return s;
    };

    float T = sweep(v1) + sweep(v2);

    // diagonal 8x8 squares: 64 pairs per tile, one per lane (waves 0 and 1)
    float Dc = 0.0f;
    if (t < 128) {
        const int v = (t < 64) ? v1 : v2;
        const int l = t & 63;
        const int i = v * TILE + (l >> 3);
        const int k = v * TILE + (l & 7);
        const float dx = pts[i].x - pts[k].x;
        const float dy = pts[i].y - pts[k].y;
        const float d2 = __builtin_fmaf(dx, dx, __builtin_fmaf(dy, dy, 1.0f));
        Dc = __builtin_amdgcn_rcpf(d2);
    }
    float part = __builtin_fmaf(2.0f, T, -Dc);   // block share of S_all

    // ---- phase 2: edge math on prefetched registers; points from LDS ----
    float s1 = 0.0f, sp = 0.0f;
    {
        float2 pa = pts[ea.x], pb = pts[eb.x];
        float dx = pa.x - pb.x, dy = pa.y - pb.y;
        float d2 = __builtin_fmaf(dx, dx, __builtin_fmaf(dy, dy, 2.0f));
        s1 += pp.x * (__logf(pp.x) + __logf(d2));
        sp += pp.x;

        pa = pts[ea.y]; pb = pts[eb.y];
        dx = pa.x - pb.x; dy = pa.y - pb.y;
        d2 = __builtin_fmaf(dx, dx, __builtin_fmaf(dy, dy, 2.0f));
        s1 += pp.y * (__logf(pp.y) + __logf(d2));
        sp += pp.y;
    }

    // ---- block reduction ----
    #pragma unroll
    for (int off = 32; off > 0; off >>= 1) {
        part += __shfl_down(part, off, 64);
        s1   += __shfl_down(s1,   off, 64);
        sp   += __shfl_down(sp,   off, 64);
    }
    const int w = t >> 6, l = t & 63;
    if (l == 0) { wred[0][w] = part; wred[1][w] = s1; wred[2][w] = sp; }
    __syncthreads();
    if (t == 0) {
        float r0s = 0.f, r1s = 0.f, r2s = 0.f;
        #pragma unroll
        for (int i = 0; i < THREADS / 64; ++i) {
            r0s += wred[0][i]; r1s += wred[1][i]; r2s += wred[2][i];
        }
        partials[0 * BLOCKS + b] = r0s;
        partials[1 * BLOCKS + b] = r1s;
        partials[2 * BLOCKS + b] = r2s;
    }
}

// ---------------- Final reduce + combine (double precision) ----------------
__global__ __launch_bounds__(256)
void final_kernel(const float* __restrict__ partials, float* __restrict__ out) {
    __shared__ double ra[4], rs[4], rp[4];
    const int t = threadIdx.x;

    double a = (double)partials[0 * BLOCKS + t] + (double)partials[0 * BLOCKS + t + 256];
    double s = (double)partials[1 * BLOCKS + t] + (double)partials[1 * BLOCKS + t + 256];
    double p = (double)partials[2 * BLOCKS + t] + (double)partials[2 * BLOCKS + t + 256];

    #pragma unroll
    for (int off = 32; off > 0; off >>= 1) {
        a += __shfl_down(a, off, 64);
        s += __shfl_down(s, off, 64);
        p += __shfl_down(p, off, 64);
    }
    const int w = t >> 6, l = t & 63;
    if (l == 0) { ra[w] = a; rs[w] = s; rp[w] = p; }
    __syncthreads();
    if (t == 0) {
        double A = 0.0, S = 0.0, P = 0.0;
        #pragma unroll
        for (int i = 0; i < 4; ++i) { A += ra[i]; S += rs[i]; P += rp[i]; }
        A -= (double)N_POINTS;                 // remove diagonal (each term == 1)
        out[0] = (float)(S + log(A) * P);
    }
}

extern "C" void kernel_launch(void* const* d_in, const int* in_sizes, int n_in,
                              void* d_out, int out_size, void* d_ws, size_t ws_size,
                              hipStream_t stream) {
    const float* pij    = (const float*)d_in[0];
    const int*   ei     = (const int*)d_in[1];
    const int*   ej     = (const int*)d_in[2];
    const float* logits = (const float*)d_in[3];
    float* out = (float*)d_out;

    float* partials = (float*)d_ws;              // 3 * BLOCKS floats

    fused_kernel<<<BLOCKS, THREADS, 0, stream>>>(logits, pij, ei, ej, partials);
    final_kernel<<<1, 256, 0, stream>>>(partials, out);
}